// Round 1
// baseline (763.923 us; speedup 1.0000x reference)
//
#include <hip/hip_runtime.h>
#include <cstddef>

// Problem constants
constexpr int B_ = 64, C_ = 128, T_ = 1024, OPC_ = 4, K_ = 5, H_ = 512, ENC_ = 512;
#define ALPHA_F 0.9512294245007140f
#define ONEMA_F 0.0487705754992860f

// ---------------------------------------------------------------------------
// Kernel 0: fold the cross-channel gate into the output weights.
// W_eff = (I + gate) @ w2   (128 x 512),  b_eff = (I + gate) @ b2
// gate = output_gates with zero diagonal.
// ---------------------------------------------------------------------------
__global__ __launch_bounds__(128) void k_weff(
    const float* __restrict__ w2, const float* __restrict__ b2,
    const float* __restrict__ og, float* __restrict__ Weff,
    float* __restrict__ beff)
{
    const int c = blockIdx.x;     // 0..127
    const int tid = threadIdx.x;  // 0..127
    __shared__ float ogs[C_];
    float g = og[c * C_ + tid];
    if (tid == c) g = 0.f;
    ogs[tid] = g;
    __syncthreads();

    float acc[4];
#pragma unroll
    for (int s = 0; s < 4; ++s) acc[s] = w2[c * H_ + tid + s * 128];
    for (int cp = 0; cp < C_; ++cp) {
        const float w = ogs[cp];
#pragma unroll
        for (int s = 0; s < 4; ++s) acc[s] += w * w2[cp * H_ + tid + s * 128];
    }
#pragma unroll
    for (int s = 0; s < 4; ++s) Weff[c * H_ + tid + s * 128] = acc[s];

    if (tid == 0) {
        float a = b2[c];
        for (int cp = 0; cp < C_; ++cp) a += ogs[cp] * b2[cp];
        beff[c] = a;
    }
}

// ---------------------------------------------------------------------------
// Kernel 1: hid[b*T+t][h] = conv(x)[t,b,:] @ w1^T + b1, conv fused into A-tile
// staging. Tile: BM=128 (t), BN=64 (h), BK=16 (enc channel e). 256 threads,
// 8x4 micro-tile per thread.
// enc(r=(b,t), e) = cb[e] + sum_{k=0..4} cw[e*5+k] * x[b][e/4][t+k-2]
// ---------------------------------------------------------------------------
__global__ __launch_bounds__(256) void k_gemm1(
    const float* __restrict__ x, const float* __restrict__ cw,
    const float* __restrict__ cb, const float* __restrict__ w1,
    const float* __restrict__ b1, float* __restrict__ hid)
{
    const int rowt = blockIdx.x;        // 0..511
    const int b = rowt >> 3;
    const int t0 = (rowt & 7) << 7;     // 128-aligned t tile
    const int h0 = blockIdx.y << 6;     // 64-wide h tile
    const int tid = threadIdx.x;
    const int tr = tid >> 4;            // 0..15 -> rows tr*8..+7
    const int tc = tid & 15;            // 0..15 -> cols tc*4..+3

    __shared__ float xs[4][132];        // 4 input channels x (128+K-1) taps
    __shared__ float As[16][128];       // As[k][m]  (enc tile, transposed)
    __shared__ float Bs[16][64];        // Bs[k][n]  (w1 tile, transposed)

    float acc[8][4];
#pragma unroll
    for (int i = 0; i < 8; ++i)
#pragma unroll
        for (int j = 0; j < 4; ++j) acc[i][j] = 0.f;

    for (int e0 = 0; e0 < ENC_; e0 += 16) {
        __syncthreads();  // previous iteration's LDS reads done

        // stage Bs: 64 h rows x 16 e, one float4 per thread
        {
            const int n = tid >> 2;            // 0..63
            const int k4 = (tid & 3) << 2;     // 0,4,8,12
            const float4 v = *reinterpret_cast<const float4*>(
                &w1[(h0 + n) * ENC_ + e0 + k4]);
            Bs[k4 + 0][n] = v.x; Bs[k4 + 1][n] = v.y;
            Bs[k4 + 2][n] = v.z; Bs[k4 + 3][n] = v.w;
        }
        // stage xs: 4 channels x 132 taps (zero-padded at t boundaries)
        const int c0 = e0 >> 2;
        for (int idx = tid; idx < 4 * 132; idx += 256) {
            const int cc = idx / 132;
            const int j = idx - cc * 132;
            const int t = t0 - 2 + j;
            float v = 0.f;
            if (t >= 0 && t < T_) v = x[(b * C_ + c0 + cc) * T_ + t];
            xs[cc][j] = v;
        }
        __syncthreads();  // xs ready

        // build As (the conv output tile) from xs
#pragma unroll
        for (int s = 0; s < 8; ++s) {
            const int idx = tid + s * 256;   // 0..2047
            const int ke = idx >> 7;         // 0..15
            const int m = idx & 127;         // 0..127
            const int e = e0 + ke;
            const float* w = &cw[e * 5];
            float v = cb[e];
#pragma unroll
            for (int k = 0; k < K_; ++k) v += w[k] * xs[ke >> 2][m + k];
            As[ke][m] = v;
        }
        __syncthreads();  // As/Bs ready

#pragma unroll
        for (int k = 0; k < 16; ++k) {
            float a[8], bb[4];
            *reinterpret_cast<float4*>(&a[0]) =
                *reinterpret_cast<const float4*>(&As[k][tr * 8]);
            *reinterpret_cast<float4*>(&a[4]) =
                *reinterpret_cast<const float4*>(&As[k][tr * 8 + 4]);
            *reinterpret_cast<float4*>(&bb[0]) =
                *reinterpret_cast<const float4*>(&Bs[k][tc * 4]);
#pragma unroll
            for (int i = 0; i < 8; ++i)
#pragma unroll
                for (int j = 0; j < 4; ++j) acc[i][j] += a[i] * bb[j];
        }
    }

    // epilogue: add b1, store (coalesced float4)
    const float4 bias = *reinterpret_cast<const float4*>(&b1[h0 + tc * 4]);
#pragma unroll
    for (int i = 0; i < 8; ++i) {
        float4 o;
        o.x = acc[i][0] + bias.x;
        o.y = acc[i][1] + bias.y;
        o.z = acc[i][2] + bias.z;
        o.w = acc[i][3] + bias.w;
        const size_t row = (size_t)(b * T_ + t0 + tr * 8 + i);
        *reinterpret_cast<float4*>(&hid[row * H_ + h0 + tc * 4]) = o;
    }
}

// ---------------------------------------------------------------------------
// Kernel 2: LIF recurrence, elementwise-independent per (b,h), in place.
// mem = ALPHA*mem + (1-ALPHA)*hid; spike = mem>=1; mem *= (1-spike); store mem.
// ---------------------------------------------------------------------------
__global__ __launch_bounds__(128) void k_recur(float* __restrict__ hid)
{
    const int bx = blockIdx.x;                     // 0..255
    const int b = bx >> 2;
    const int h = ((bx & 3) << 7) + threadIdx.x;   // 0..511
    float mem = 0.f;
    const size_t base = (size_t)b * T_ * H_ + h;
    for (int t0 = 0; t0 < T_; t0 += 8) {
        float v[8];
#pragma unroll
        for (int i = 0; i < 8; ++i) v[i] = hid[base + (size_t)(t0 + i) * H_];
#pragma unroll
        for (int i = 0; i < 8; ++i) {
            mem = ALPHA_F * mem + ONEMA_F * v[i];
            mem = (mem >= 1.0f) ? 0.f : mem;
            v[i] = mem;
        }
#pragma unroll
        for (int i = 0; i < 8; ++i) hid[base + (size_t)(t0 + i) * H_] = v[i];
    }
}

// ---------------------------------------------------------------------------
// Kernel 3: out[b][c][t] = W_eff @ mem_b^T + b_eff, stores directly in (B,C,T).
// Tile: 128 c-rows x 64 r-cols, K=512. 256 threads, 8x4 micro-tile.
// ---------------------------------------------------------------------------
__global__ __launch_bounds__(256) void k_gemm2(
    const float* __restrict__ memr, const float* __restrict__ Weff,
    const float* __restrict__ beff, float* __restrict__ out)
{
    const int r0 = blockIdx.x << 6;    // 64 rows (b*T+t), within one b
    const int b = r0 >> 10;
    const int t0 = r0 & 1023;
    const int tid = threadIdx.x;
    const int tr = tid >> 4;           // rows c = tr*8..+7
    const int tc = tid & 15;           // cols (t) = tc*4..+3

    __shared__ float As[16][128];      // As[k][c] from Weff
    __shared__ float Bs[16][64];       // Bs[k][n] from memr rows r0+n

    float acc[8][4];
#pragma unroll
    for (int i = 0; i < 8; ++i)
#pragma unroll
        for (int j = 0; j < 4; ++j) acc[i][j] = 0.f;

    for (int e0 = 0; e0 < H_; e0 += 16) {
        __syncthreads();
#pragma unroll
        for (int s = 0; s < 2; ++s) {
            const int idx = tid + s * 256;   // 0..511
            const int c = idx >> 2;          // 0..127
            const int k4 = (idx & 3) << 2;
            const float4 v = *reinterpret_cast<const float4*>(
                &Weff[c * H_ + e0 + k4]);
            As[k4 + 0][c] = v.x; As[k4 + 1][c] = v.y;
            As[k4 + 2][c] = v.z; As[k4 + 3][c] = v.w;
        }
        {
            const int n = tid >> 2;          // 0..63
            const int k4 = (tid & 3) << 2;
            const float4 v = *reinterpret_cast<const float4*>(
                &memr[(size_t)(r0 + n) * H_ + e0 + k4]);
            Bs[k4 + 0][n] = v.x; Bs[k4 + 1][n] = v.y;
            Bs[k4 + 2][n] = v.z; Bs[k4 + 3][n] = v.w;
        }
        __syncthreads();

#pragma unroll
        for (int k = 0; k < 16; ++k) {
            float a[8], bb[4];
            *reinterpret_cast<float4*>(&a[0]) =
                *reinterpret_cast<const float4*>(&As[k][tr * 8]);
            *reinterpret_cast<float4*>(&a[4]) =
                *reinterpret_cast<const float4*>(&As[k][tr * 8 + 4]);
            *reinterpret_cast<float4*>(&bb[0]) =
                *reinterpret_cast<const float4*>(&Bs[k][tc * 4]);
#pragma unroll
            for (int i = 0; i < 8; ++i)
#pragma unroll
                for (int j = 0; j < 4; ++j) acc[i][j] += a[i] * bb[j];
        }
    }

    // epilogue: out[(b*C + c)*T + t], float4 over t (coalesced)
#pragma unroll
    for (int i = 0; i < 8; ++i) {
        const int c = tr * 8 + i;
        const float bi = beff[c];
        float4 o;
        o.x = acc[i][0] + bi; o.y = acc[i][1] + bi;
        o.z = acc[i][2] + bi; o.w = acc[i][3] + bi;
        *reinterpret_cast<float4*>(
            &out[((size_t)(b * C_ + c)) * T_ + t0 + tc * 4]) = o;
    }
}

// ---------------------------------------------------------------------------
extern "C" void kernel_launch(void* const* d_in, const int* in_sizes, int n_in,
                              void* d_out, int out_size, void* d_ws, size_t ws_size,
                              hipStream_t stream)
{
    const float* x   = (const float*)d_in[0];
    const float* cw  = (const float*)d_in[1];
    const float* cb  = (const float*)d_in[2];
    const float* w1  = (const float*)d_in[3];
    const float* b1  = (const float*)d_in[4];
    const float* w2  = (const float*)d_in[5];
    const float* b2  = (const float*)d_in[6];
    const float* og  = (const float*)d_in[7];

    float* hid  = (float*)d_ws;                          // 65536 x 512 fp32
    float* Weff = hid + (size_t)B_ * T_ * H_;            // 128 x 512
    float* beff = Weff + (size_t)C_ * H_;                // 128

    k_weff<<<dim3(C_), dim3(128), 0, stream>>>(w2, b2, og, Weff, beff);

    dim3 g1(512, 8);
    k_gemm1<<<g1, dim3(256), 0, stream>>>(x, cw, cb, w1, b1, hid);

    k_recur<<<dim3(256), dim3(128), 0, stream>>>(hid);

    k_gemm2<<<dim3(1024), dim3(256), 0, stream>>>(hid, Weff, beff, (float*)d_out);
}

// Round 2
// 345.896 us; speedup vs baseline: 2.2085x; 2.2085x over previous
//
#include <hip/hip_runtime.h>
#include <cstddef>
#include <cstdint>

constexpr int B_ = 64, C_ = 128, T_ = 1024, H_ = 512, ENC_ = 512;
#define ALPHA_F 0.9512294245007140f
#define ONEMA_F 0.0487705754992860f

typedef short v8s __attribute__((ext_vector_type(8)));
typedef float v4f __attribute__((ext_vector_type(4)));

__device__ __forceinline__ unsigned short f2bf(float f) {
    union { float f; unsigned u; } v; v.f = f;
    unsigned r = v.u + 0x7FFFu + ((v.u >> 16) & 1u);
    return (unsigned short)(r >> 16);
}
__device__ __forceinline__ float bf2f(unsigned short h) {
    union { unsigned u; float f; } v; v.u = ((unsigned)h) << 16;
    return v.f;
}
__device__ __forceinline__ int4 pack8(float4 a, float4 b) {
    int4 r;
    r.x = (int)f2bf(a.x) | ((int)f2bf(a.y) << 16);
    r.y = (int)f2bf(a.z) | ((int)f2bf(a.w) << 16);
    r.z = (int)f2bf(b.x) | ((int)f2bf(b.y) << 16);
    r.w = (int)f2bf(b.z) | ((int)f2bf(b.w) << 16);
    return r;
}

// ---------------------------------------------------------------------------
// cast w1 (fp32) -> bf16, vectorized
// ---------------------------------------------------------------------------
__global__ __launch_bounds__(256) void k_cast(
    const float* __restrict__ in, unsigned short* __restrict__ out, int n4)
{
    int i = blockIdx.x * 256 + threadIdx.x;
    if (i < n4) {
        float4 v = ((const float4*)in)[i];
        ushort4 h;
        h.x = f2bf(v.x); h.y = f2bf(v.y); h.z = f2bf(v.z); h.w = f2bf(v.w);
        ((ushort4*)out)[i] = h;
    }
}

// ---------------------------------------------------------------------------
// W_eff = (I + gate) @ w2 (fp32), b_eff = (I + gate) @ b2
// ---------------------------------------------------------------------------
__global__ __launch_bounds__(128) void k_weff(
    const float* __restrict__ w2, const float* __restrict__ b2,
    const float* __restrict__ og, float* __restrict__ Weff,
    float* __restrict__ beff)
{
    const int c = blockIdx.x;
    const int tid = threadIdx.x;
    __shared__ float ogs[C_];
    float g = og[c * C_ + tid];
    if (tid == c) g = 0.f;
    ogs[tid] = g;
    __syncthreads();

    float acc[4];
#pragma unroll
    for (int s = 0; s < 4; ++s) acc[s] = w2[c * H_ + tid + s * 128];
    for (int cp = 0; cp < C_; ++cp) {
        const float w = ogs[cp];
#pragma unroll
        for (int s = 0; s < 4; ++s) acc[s] += w * w2[cp * H_ + tid + s * 128];
    }
#pragma unroll
    for (int s = 0; s < 4; ++s) Weff[c * H_ + tid + s * 128] = acc[s];

    if (tid == 0) {
        float a = b2[c];
        for (int cp = 0; cp < C_; ++cp) a += ogs[cp] * b2[cp];
        beff[c] = a;
    }
}

// ---------------------------------------------------------------------------
// depthwise conv (K=5, same-pad) -> enc bf16 [B*T][ENC]
// block: (b, 128-t tile); 4 channel-chunks of 32
// ---------------------------------------------------------------------------
__global__ __launch_bounds__(256) void k_conv(
    const float* __restrict__ x, const float* __restrict__ cw,
    const float* __restrict__ cb, unsigned short* __restrict__ enc)
{
    const int b = blockIdx.x >> 3;
    const int t0 = (blockIdx.x & 7) << 7;
    const int tid = threadIdx.x;
    __shared__ float xs[32][133];
    __shared__ float cwc[128][5];
    __shared__ float cbc[128];
    const int c_l = tid & 31, tl0 = tid >> 5;

    for (int chunk = 0; chunk < 4; ++chunk) {
        const int c0 = chunk << 5;
        __syncthreads();
        for (int i = tid; i < 32 * 132; i += 256) {
            int c = i / 132, j = i - c * 132;
            int t = t0 - 2 + j;
            float v = 0.f;
            if (t >= 0 && t < T_) v = x[((size_t)b * C_ + c0 + c) * T_ + t];
            xs[c][j] = v;
        }
        for (int i = tid; i < 640; i += 256) {
            int e = i / 5, k = i - e * 5;
            cwc[e][k] = cw[(size_t)(c0 * 4 + e) * 5 + k];
        }
        if (tid < 128) cbc[tid] = cb[c0 * 4 + tid];
        __syncthreads();
#pragma unroll
        for (int tt = 0; tt < 16; ++tt) {
            const int tl = tl0 + (tt << 3);
            const float x0 = xs[c_l][tl], x1 = xs[c_l][tl + 1],
                        x2 = xs[c_l][tl + 2], x3 = xs[c_l][tl + 3],
                        x4 = xs[c_l][tl + 4];
            ushort4 hv;
#pragma unroll
            for (int o = 0; o < 4; ++o) {
                const int e = (c_l << 2) + o;
                float a = cbc[e] + cwc[e][0] * x0 + cwc[e][1] * x1 +
                          cwc[e][2] * x2 + cwc[e][3] * x3 + cwc[e][4] * x4;
                ((unsigned short*)&hv)[o] = f2bf(a);
            }
            *(ushort4*)(&enc[((size_t)(b * T_ + t0 + tl) << 9) +
                             ((c0 + c_l) << 2)]) = hv;
        }
    }
}

// ---------------------------------------------------------------------------
// bf16 MFMA GEMM, 128x128 tile, BK=64, 4 waves, XOR-swizzled LDS.
// MODE 0: D[m=(b,t)][n=h] = enc @ w1b^T; out hid bf16; bias=b1[n].
//         grid 2048 1-D, XCD-aware tile remap (4 n-tiles per A-panel).
// MODE 1: D[m=c][n=(b,t)] = Weff(fp32,cast) @ mem^T; out fp32 (B,C,T); bias=beff[m].
//         grid 512 1-D.
// ---------------------------------------------------------------------------
template<int MODE>
__global__ __launch_bounds__(256) void k_mfma(
    const void* __restrict__ Ap, const void* __restrict__ Bp,
    const float* __restrict__ bias, void* __restrict__ outp)
{
    __shared__ unsigned char lds[32768];  // As 16KB | Bs 16KB
    const int tid = threadIdx.x;
    const int lane = tid & 63;
    const int w = tid >> 6;
    const int wm = (w & 1) << 6, wn = (w >> 1) << 6;

    int m0, n0;
    if (MODE == 0) {
        const int d = blockIdx.x;          // dispatch-order linear
        const int g = ((d & 7) << 8) + (d >> 3);  // XCD k -> contiguous tiles
        m0 = (g >> 2) << 7;
        n0 = (g & 3) << 7;
    } else {
        m0 = 0;
        n0 = blockIdx.x << 7;
    }

    v4f acc[4][4];
#pragma unroll
    for (int i = 0; i < 4; ++i)
#pragma unroll
        for (int j = 0; j < 4; ++j) acc[i][j] = (v4f)0.f;

    for (int k0 = 0; k0 < 512; k0 += 64) {
        int4 sa[4], sb[4];
#pragma unroll
        for (int q = 0; q < 4; ++q) {
            const int L = q * 4096 + tid * 16;
            const int row = L >> 7, kb = L & 127;
            if (MODE == 0) {
                sa[q] = *(const int4*)((const unsigned short*)Ap +
                        (size_t)(m0 + row) * 512 + k0 + (kb >> 1));
            } else {
                const float* ap = (const float*)Ap + (size_t)row * 512 + k0 + (kb >> 1);
                sa[q] = pack8(*(const float4*)ap, *(const float4*)(ap + 4));
            }
            sb[q] = *(const int4*)((const unsigned short*)Bp +
                    (size_t)(n0 + row) * 512 + k0 + (kb >> 1));
        }
        __syncthreads();  // prior compute finished with LDS
#pragma unroll
        for (int q = 0; q < 4; ++q) {
            const int L = q * 4096 + tid * 16;
            const int row = L >> 7, kb = L & 127;
            const int dst = row * 128 + (kb ^ ((row & 7) << 4));
            *(int4*)(lds + dst) = sa[q];
            *(int4*)(lds + 16384 + dst) = sb[q];
        }
        __syncthreads();
#pragma unroll
        for (int ks = 0; ks < 2; ++ks) {
            v8s af[4], bfr[4];
#pragma unroll
            for (int i = 0; i < 4; ++i) {
                const int ra = wm + i * 16 + (lane & 15);
                const int rb = wn + i * 16 + (lane & 15);
                const int kb = ks * 64 + ((lane >> 4) << 4);
                af[i]  = *(const v8s*)(lds + ra * 128 + (kb ^ ((ra & 7) << 4)));
                bfr[i] = *(const v8s*)(lds + 16384 + rb * 128 + (kb ^ ((rb & 7) << 4)));
            }
#pragma unroll
            for (int mi = 0; mi < 4; ++mi)
#pragma unroll
                for (int ni = 0; ni < 4; ++ni)
                    acc[mi][ni] = __builtin_amdgcn_mfma_f32_16x16x32_bf16(
                        af[mi], bfr[ni], acc[mi][ni], 0, 0, 0);
        }
    }

    if (MODE == 0) {
        unsigned short* out = (unsigned short*)outp;
#pragma unroll
        for (int mi = 0; mi < 4; ++mi)
#pragma unroll
            for (int ni = 0; ni < 4; ++ni) {
                const int n = n0 + wn + ni * 16 + (lane & 15);
                const float bi = bias[n];
#pragma unroll
                for (int r = 0; r < 4; ++r) {
                    const int m = m0 + wm + mi * 16 + ((lane >> 4) << 2) + r;
                    out[(size_t)m * 512 + n] = f2bf(acc[mi][ni][r] + bi);
                }
            }
    } else {
        float* out = (float*)outp;
#pragma unroll
        for (int mi = 0; mi < 4; ++mi)
#pragma unroll
            for (int ni = 0; ni < 4; ++ni) {
                const int n = n0 + wn + ni * 16 + (lane & 15);  // (b,t) row
                const int b = n >> 10, t = n & 1023;
#pragma unroll
                for (int r = 0; r < 4; ++r) {
                    const int c = wm + mi * 16 + ((lane >> 4) << 2) + r;
                    out[((size_t)(b * C_ + c) << 10) + t] = acc[mi][ni][r] + bias[c];
                }
            }
    }
}

// ---------------------------------------------------------------------------
// LIF recurrence, in-place on bf16 hid. 2 h per lane, 1 wave per block.
// ---------------------------------------------------------------------------
__global__ __launch_bounds__(64) void k_recur(unsigned short* __restrict__ hid)
{
    const int b = blockIdx.x >> 2;
    const int h = ((blockIdx.x & 3) << 7) + (threadIdx.x << 1);
    unsigned int* p = (unsigned int*)hid + (size_t)b * 262144 + (h >> 1);
    float ma = 0.f, mb = 0.f;
    for (int t0 = 0; t0 < T_; t0 += 16) {
        unsigned int v[16];
#pragma unroll
        for (int i = 0; i < 16; ++i) v[i] = p[(size_t)(t0 + i) * 256];
#pragma unroll
        for (int i = 0; i < 16; ++i) {
            const float v0 = bf2f((unsigned short)(v[i] & 0xFFFFu));
            const float v1 = bf2f((unsigned short)(v[i] >> 16));
            ma = ALPHA_F * ma + ONEMA_F * v0;
            ma = (ma >= 1.0f) ? 0.f : ma;
            mb = ALPHA_F * mb + ONEMA_F * v1;
            mb = (mb >= 1.0f) ? 0.f : mb;
            v[i] = (unsigned)f2bf(ma) | ((unsigned)f2bf(mb) << 16);
        }
#pragma unroll
        for (int i = 0; i < 16; ++i) p[(size_t)(t0 + i) * 256] = v[i];
    }
}

// ---------------------------------------------------------------------------
extern "C" void kernel_launch(void* const* d_in, const int* in_sizes, int n_in,
                              void* d_out, int out_size, void* d_ws, size_t ws_size,
                              hipStream_t stream)
{
    const float* x   = (const float*)d_in[0];
    const float* cw  = (const float*)d_in[1];
    const float* cb  = (const float*)d_in[2];
    const float* w1  = (const float*)d_in[3];
    const float* b1  = (const float*)d_in[4];
    const float* w2  = (const float*)d_in[5];
    const float* b2  = (const float*)d_in[6];
    const float* og  = (const float*)d_in[7];

    char* ws = (char*)d_ws;
    unsigned short* enc  = (unsigned short*)ws;                    // 67,108,864 B
    unsigned short* hid  = (unsigned short*)(ws + 67108864);       // 67,108,864 B
    float*          Weff = (float*)(ws + 134217728);               // 262,144 B
    float*          beff = (float*)(ws + 134479872);               // 512 B
    unsigned short* w1b  = (unsigned short*)d_out;                 // temp, dead before gemm2 writes

    k_cast<<<256, 256, 0, stream>>>(w1, w1b, 65536);
    k_conv<<<512, 256, 0, stream>>>(x, cw, cb, enc);
    k_weff<<<128, 128, 0, stream>>>(w2, b2, og, Weff, beff);

    k_mfma<0><<<2048, 256, 0, stream>>>(enc, w1b, b1, hid);
    k_recur<<<256, 64, 0, stream>>>(hid);
    k_mfma<1><<<512, 256, 0, stream>>>(Weff, hid, beff, (float*)d_out);
}

// Round 3
// 184.032 us; speedup vs baseline: 4.1510x; 1.8795x over previous
//
#include <hip/hip_runtime.h>
#include <cstddef>
#include <cstdint>

constexpr int B_ = 64, C_ = 128, T_ = 1024, H_ = 512, ENC_ = 512;
#define ALPHA_F 0.9512294245007140f
#define ONEMA_F 0.0487705754992860f

typedef short v8s __attribute__((ext_vector_type(8)));
typedef float v4f __attribute__((ext_vector_type(4)));

#define GL16(gp, lp) __builtin_amdgcn_global_load_lds( \
    (const __attribute__((address_space(1))) unsigned int*)(gp), \
    (__attribute__((address_space(3))) unsigned int*)(lp), 16, 0, 0)

__device__ __forceinline__ unsigned short f2bf(float f) {
    union { float f; unsigned u; } v; v.f = f;
    unsigned r = v.u + 0x7FFFu + ((v.u >> 16) & 1u);
    return (unsigned short)(r >> 16);
}
__device__ __forceinline__ float bf2f(unsigned short h) {
    union { unsigned u; float f; } v; v.u = ((unsigned)h) << 16;
    return v.f;
}

// ---------------------------------------------------------------------------
// cast w1 (fp32) -> bf16
// ---------------------------------------------------------------------------
__global__ __launch_bounds__(256) void k_cast(
    const float* __restrict__ in, unsigned short* __restrict__ out, int n4)
{
    int i = blockIdx.x * 256 + threadIdx.x;
    if (i < n4) {
        float4 v = ((const float4*)in)[i];
        ushort4 h;
        h.x = f2bf(v.x); h.y = f2bf(v.y); h.z = f2bf(v.z); h.w = f2bf(v.w);
        ((ushort4*)out)[i] = h;
    }
}

// ---------------------------------------------------------------------------
// W_eff = (I + gate) @ w2 -> bf16,  b_eff = (I + gate) @ b2 -> fp32
// ---------------------------------------------------------------------------
__global__ __launch_bounds__(128) void k_weff(
    const float* __restrict__ w2, const float* __restrict__ b2,
    const float* __restrict__ og, unsigned short* __restrict__ Weffb,
    float* __restrict__ beff)
{
    const int c = blockIdx.x;
    const int tid = threadIdx.x;
    __shared__ float ogs[C_];
    float g = og[c * C_ + tid];
    if (tid == c) g = 0.f;
    ogs[tid] = g;
    __syncthreads();

    float acc[4];
#pragma unroll
    for (int s = 0; s < 4; ++s) acc[s] = w2[c * H_ + tid + s * 128];
    for (int cp = 0; cp < C_; ++cp) {
        const float w = ogs[cp];
#pragma unroll
        for (int s = 0; s < 4; ++s) acc[s] += w * w2[cp * H_ + tid + s * 128];
    }
#pragma unroll
    for (int s = 0; s < 4; ++s) Weffb[c * H_ + tid + s * 128] = f2bf(acc[s]);

    if (tid == 0) {
        float a = b2[c];
        for (int cp = 0; cp < C_; ++cp) a += ogs[cp] * b2[cp];
        beff[c] = a;
    }
}

// ---------------------------------------------------------------------------
// depthwise conv (K=5, same-pad) -> enc bf16 [B*T][ENC]
// ---------------------------------------------------------------------------
__global__ __launch_bounds__(256) void k_conv(
    const float* __restrict__ x, const float* __restrict__ cw,
    const float* __restrict__ cb, unsigned short* __restrict__ enc)
{
    const int b = blockIdx.x >> 3;
    const int t0 = (blockIdx.x & 7) << 7;
    const int tid = threadIdx.x;
    __shared__ float xs[32][133];
    __shared__ float cwc[128][5];
    __shared__ float cbc[128];
    const int c_l = tid & 31, tl0 = tid >> 5;

    for (int chunk = 0; chunk < 4; ++chunk) {
        const int c0 = chunk << 5;
        __syncthreads();
        for (int i = tid; i < 32 * 132; i += 256) {
            int c = i / 132, j = i - c * 132;
            int t = t0 - 2 + j;
            float v = 0.f;
            if (t >= 0 && t < T_) v = x[((size_t)b * C_ + c0 + c) * T_ + t];
            xs[c][j] = v;
        }
        for (int i = tid; i < 640; i += 256) {
            int e = i / 5, k = i - e * 5;
            cwc[e][k] = cw[(size_t)(c0 * 4 + e) * 5 + k];
        }
        if (tid < 128) cbc[tid] = cb[c0 * 4 + tid];
        __syncthreads();
#pragma unroll
        for (int tt = 0; tt < 16; ++tt) {
            const int tl = tl0 + (tt << 3);
            const float x0 = xs[c_l][tl], x1 = xs[c_l][tl + 1],
                        x2 = xs[c_l][tl + 2], x3 = xs[c_l][tl + 3],
                        x4 = xs[c_l][tl + 4];
            ushort4 hv;
#pragma unroll
            for (int o = 0; o < 4; ++o) {
                const int e = (c_l << 2) + o;
                float a = cbc[e] + cwc[e][0] * x0 + cwc[e][1] * x1 +
                          cwc[e][2] * x2 + cwc[e][3] * x3 + cwc[e][4] * x4;
                ((unsigned short*)&hv)[o] = f2bf(a);
            }
            *(ushort4*)(&enc[((size_t)(b * T_ + t0 + tl) << 9) +
                             ((c0 + c_l) << 2)]) = hv;
        }
    }
}

// ---------------------------------------------------------------------------
// bf16 MFMA GEMM, 128x128 tile, BK=64, 4 waves. global_load_lds staging with
// inverse-swizzled SOURCE (rule 21): LDS dest linear, reads XOR-swizzled.
// MODE 0: D[m=(b,t)][n=h] = enc @ w1b^T + b1; out bf16, LDS-staged coalesced.
// MODE 1: D[m=c][n=(b,t)] = Weffb @ mem^T + beff; out fp32 direct (B,C,T).
// ---------------------------------------------------------------------------
template<int MODE>
__global__ __launch_bounds__(256) void k_mfma(
    const unsigned short* __restrict__ A, const unsigned short* __restrict__ Bm,
    const float* __restrict__ bias, void* __restrict__ outp)
{
    __shared__ unsigned char lds[32768];  // As 16KB | Bs 16KB
    const int tid = threadIdx.x;
    const int lane = tid & 63;
    const int w = tid >> 6;
    const int wm = (w & 1) << 6, wn = (w >> 1) << 6;

    int m0, n0;
    if (MODE == 0) {
        const int d = blockIdx.x;
        const int g = ((d & 7) << 8) + (d >> 3);  // XCD-contiguous tiles
        m0 = (g >> 2) << 7;
        n0 = (g & 3) << 7;
    } else {
        m0 = 0;
        n0 = blockIdx.x << 7;
    }

    // pre-swizzled per-lane global source: LDS row = 8-row groups, 128B k-slice
    const int lrow = lane >> 3;                  // row within 8-row group
    const int lcol = ((lane & 7) ^ lrow) << 4;   // swizzled 16B slot
    const unsigned char* pA = (const unsigned char*)A +
        (size_t)(m0 + w * 32 + lrow) * 1024 + lcol;
    const unsigned char* pB = (const unsigned char*)Bm +
        (size_t)(n0 + w * 32 + lrow) * 1024 + lcol;
    unsigned char* lA = lds + w * 4096;
    unsigned char* lB = lds + 16384 + w * 4096;

    v4f acc[4][4];
#pragma unroll
    for (int i = 0; i < 4; ++i)
#pragma unroll
        for (int j = 0; j < 4; ++j) acc[i][j] = (v4f)0.f;

    for (int k0 = 0; k0 < 512; k0 += 64) {
        __syncthreads();  // prior iteration's LDS reads done
#pragma unroll
        for (int i = 0; i < 4; ++i) {
            GL16(pA + (size_t)i * 8192 + k0 * 2, lA + i * 1024);
            GL16(pB + (size_t)i * 8192 + k0 * 2, lB + i * 1024);
        }
        __syncthreads();  // vmcnt drain: tiles resident
#pragma unroll
        for (int ks = 0; ks < 2; ++ks) {
            v8s af[4], bfr[4];
#pragma unroll
            for (int i = 0; i < 4; ++i) {
                const int ra = wm + i * 16 + (lane & 15);
                const int rb = wn + i * 16 + (lane & 15);
                const int kb = ks * 64 + ((lane >> 4) << 4);
                af[i]  = *(const v8s*)(lds + ra * 128 + (kb ^ ((ra & 7) << 4)));
                bfr[i] = *(const v8s*)(lds + 16384 + rb * 128 + (kb ^ ((rb & 7) << 4)));
            }
#pragma unroll
            for (int mi = 0; mi < 4; ++mi)
#pragma unroll
                for (int ni = 0; ni < 4; ++ni)
                    acc[mi][ni] = __builtin_amdgcn_mfma_f32_16x16x32_bf16(
                        af[mi], bfr[ni], acc[mi][ni], 0, 0, 0);
        }
    }

    if (MODE == 0) {
        // stage C-tile (128x128 bf16 = 32KB) into LDS, swizzled; store coalesced
        __syncthreads();
#pragma unroll
        for (int mi = 0; mi < 4; ++mi)
#pragma unroll
            for (int ni = 0; ni < 4; ++ni) {
                const int n = wn + ni * 16 + (lane & 15);
                const float bi = bias[n0 + n];
#pragma unroll
                for (int r = 0; r < 4; ++r) {
                    const int m = wm + mi * 16 + ((lane >> 4) << 2) + r;
                    *(unsigned short*)(lds + m * 256 +
                        ((n * 2) ^ (((m >> 2) & 3) << 5))) =
                        f2bf(acc[mi][ni][r] + bi);
                }
            }
        __syncthreads();
        unsigned short* out = (unsigned short*)outp;
#pragma unroll
        for (int s = 0; s < 8; ++s) {
            const int idx = s * 256 + tid;
            const int r = idx >> 4, c16 = idx & 15;
            const int4 v = *(const int4*)(lds + r * 256 +
                ((c16 * 16) ^ (((r >> 2) & 3) << 5)));
            *(int4*)(&out[(size_t)(m0 + r) * 512 + n0 + c16 * 8]) = v;
        }
    } else {
        float* out = (float*)outp;
#pragma unroll
        for (int mi = 0; mi < 4; ++mi)
#pragma unroll
            for (int ni = 0; ni < 4; ++ni) {
                const int n = n0 + wn + ni * 16 + (lane & 15);  // (b,t)
                const int b = n >> 10, t = n & 1023;
#pragma unroll
                for (int r = 0; r < 4; ++r) {
                    const int c = wm + mi * 16 + ((lane >> 4) << 2) + r;
                    out[((size_t)(b * C_ + c) << 10) + t] = acc[mi][ni][r] + bias[c];
                }
            }
    }
}

// ---------------------------------------------------------------------------
// LIF recurrence. 4-way t-split with 128-step warmup (alpha^128 ~ 1.7e-3,
// |mem| ~ 0.02 << threshold 1.0 -> warmup error ~3e-4, spikes unaffected).
// Reads immutable hid (bf16), writes mem into memb (the dead enc slot).
// 256 blocks x 256 threads = 1024 waves.
// ---------------------------------------------------------------------------
__global__ __launch_bounds__(256) void k_recur(
    const unsigned int* __restrict__ hid, unsigned int* __restrict__ memb)
{
    const int j = blockIdx.x >> 6;       // t-chunk 0..3
    const int b = blockIdx.x & 63;
    const size_t base = (size_t)b * 262144 + threadIdx.x;  // uint units
    const unsigned int* pin = hid + base;
    unsigned int* pout = memb + base;
    float ma = 0.f, mb = 0.f;
    const int t0 = j << 8;

    if (j > 0) {  // warmup: read-only, mem assumed 0 at t0-128
        for (int t = t0 - 128; t < t0; t += 16) {
            unsigned int v[16];
#pragma unroll
            for (int i = 0; i < 16; ++i) v[i] = pin[(size_t)(t + i) << 8];
#pragma unroll
            for (int i = 0; i < 16; ++i) {
                ma = ALPHA_F * ma + ONEMA_F * bf2f((unsigned short)(v[i] & 0xFFFFu));
                ma = (ma >= 1.0f) ? 0.f : ma;
                mb = ALPHA_F * mb + ONEMA_F * bf2f((unsigned short)(v[i] >> 16));
                mb = (mb >= 1.0f) ? 0.f : mb;
            }
        }
    }
    for (int t = t0; t < t0 + 256; t += 16) {
        unsigned int v[16];
#pragma unroll
        for (int i = 0; i < 16; ++i) v[i] = pin[(size_t)(t + i) << 8];
#pragma unroll
        for (int i = 0; i < 16; ++i) {
            ma = ALPHA_F * ma + ONEMA_F * bf2f((unsigned short)(v[i] & 0xFFFFu));
            ma = (ma >= 1.0f) ? 0.f : ma;
            mb = ALPHA_F * mb + ONEMA_F * bf2f((unsigned short)(v[i] >> 16));
            mb = (mb >= 1.0f) ? 0.f : mb;
            v[i] = (unsigned)f2bf(ma) | ((unsigned)f2bf(mb) << 16);
        }
#pragma unroll
        for (int i = 0; i < 16; ++i) pout[(size_t)(t + i) << 8] = v[i];
    }
}

// ---------------------------------------------------------------------------
extern "C" void kernel_launch(void* const* d_in, const int* in_sizes, int n_in,
                              void* d_out, int out_size, void* d_ws, size_t ws_size,
                              hipStream_t stream)
{
    const float* x   = (const float*)d_in[0];
    const float* cw  = (const float*)d_in[1];
    const float* cb  = (const float*)d_in[2];
    const float* w1  = (const float*)d_in[3];
    const float* b1  = (const float*)d_in[4];
    const float* w2  = (const float*)d_in[5];
    const float* b2  = (const float*)d_in[6];
    const float* og  = (const float*)d_in[7];

    char* ws = (char*)d_ws;
    unsigned short* enc   = (unsigned short*)ws;               // 64 MiB (later: memb)
    unsigned short* hid   = (unsigned short*)(ws + 67108864);  // 64 MiB
    unsigned short* Weffb = (unsigned short*)(ws + 134217728); // 128 KiB
    float*          beff  = (float*)(ws + 134479872);          // 512 B
    unsigned short* w1b   = (unsigned short*)d_out;            // temp, dead before mfma<1>

    k_cast<<<256, 256, 0, stream>>>(w1, w1b, 65536);
    k_conv<<<512, 256, 0, stream>>>(x, cw, cb, enc);
    k_weff<<<128, 128, 0, stream>>>(w2, b2, og, Weffb, beff);

    k_mfma<0><<<2048, 256, 0, stream>>>(enc, w1b, b1, hid);
    k_recur<<<256, 256, 0, stream>>>((const unsigned int*)hid, (unsigned int*)enc);
    k_mfma<1><<<512, 256, 0, stream>>>(Weffb, enc, beff, (float*)d_out);
}

// Round 4
// 128.805 us; speedup vs baseline: 5.9308x; 1.4288x over previous
//
#include <hip/hip_runtime.h>
#include <cstddef>
#include <cstdint>

constexpr int B_ = 64, C_ = 128, T_ = 1024, H_ = 512, ENC_ = 512;
#define ALPHA_F 0.9512294245007140f
#define ONEMA_F 0.0487705754992860f

typedef short v8s __attribute__((ext_vector_type(8)));
typedef float v4f __attribute__((ext_vector_type(4)));

#define GL16(gp, lp) __builtin_amdgcn_global_load_lds( \
    (const __attribute__((address_space(1))) unsigned int*)(gp), \
    (__attribute__((address_space(3))) unsigned int*)(lp), 16, 0, 0)

__device__ __forceinline__ unsigned short f2bf(float f) {
    union { float f; unsigned u; } v; v.f = f;
    unsigned r = v.u + 0x7FFFu + ((v.u >> 16) & 1u);
    return (unsigned short)(r >> 16);
}
__device__ __forceinline__ float bf2f(unsigned short h) {
    union { unsigned u; float f; } v; v.u = ((unsigned)h) << 16;
    return v.f;
}

// ---------------------------------------------------------------------------
// cast w1 (fp32) -> bf16
// ---------------------------------------------------------------------------
__global__ __launch_bounds__(256) void k_cast(
    const float* __restrict__ in, unsigned short* __restrict__ out, int n4)
{
    int i = blockIdx.x * 256 + threadIdx.x;
    if (i < n4) {
        float4 v = ((const float4*)in)[i];
        ushort4 h;
        h.x = f2bf(v.x); h.y = f2bf(v.y); h.z = f2bf(v.z); h.w = f2bf(v.w);
        ((ushort4*)out)[i] = h;
    }
}

// ---------------------------------------------------------------------------
// W_eff = (I + gate) @ w2 -> bf16,  b_eff = (I + gate) @ b2 -> fp32
// ---------------------------------------------------------------------------
__global__ __launch_bounds__(128) void k_weff(
    const float* __restrict__ w2, const float* __restrict__ b2,
    const float* __restrict__ og, unsigned short* __restrict__ Weffb,
    float* __restrict__ beff)
{
    const int c = blockIdx.x;
    const int tid = threadIdx.x;
    __shared__ float ogs[C_];
    float g = og[c * C_ + tid];
    if (tid == c) g = 0.f;
    ogs[tid] = g;
    __syncthreads();

    float acc[4];
#pragma unroll
    for (int s = 0; s < 4; ++s) acc[s] = w2[c * H_ + tid + s * 128];
    for (int cp = 0; cp < C_; ++cp) {
        const float w = ogs[cp];
#pragma unroll
        for (int s = 0; s < 4; ++s) acc[s] += w * w2[cp * H_ + tid + s * 128];
    }
#pragma unroll
    for (int s = 0; s < 4; ++s) Weffb[c * H_ + tid + s * 128] = f2bf(acc[s]);

    if (tid == 0) {
        float a = b2[c];
        for (int cp = 0; cp < C_; ++cp) a += ogs[cp] * b2[cp];
        beff[c] = a;
    }
}

// ---------------------------------------------------------------------------
// depthwise conv (K=5, same-pad) -> enc bf16 [B*T][ENC]
// grid 2048 = b(64) x t-tile(8 of 128) x c-chunk(4 of 32). 256 threads.
// Weights in registers (lane owns one channel). x staged transposed:
// xs[tap][chan] (+1 pad) -> both staging writes and compute reads are
// bank-conflict-free. One __syncthreads per block.
// ---------------------------------------------------------------------------
__global__ __launch_bounds__(256) void k_conv(
    const float* __restrict__ x, const float* __restrict__ cw,
    const float* __restrict__ cb, unsigned short* __restrict__ enc)
{
    const int bid = blockIdx.x;
    const int b  = bid >> 5;
    const int t0 = ((bid >> 2) & 7) << 7;
    const int c0 = (bid & 3) << 5;
    const int tid = threadIdx.x;
    const int c_l = tid & 31;     // channel within chunk
    const int tl0 = tid >> 5;     // 0..7

    __shared__ float xs[132][33];  // [tap j][channel], +1 pad

    // per-lane weights for channel c: enc channels c*4..c*4+3
    const int c = c0 + c_l;
    float wreg[20];
    {
        const float4* wp = (const float4*)(cw + (size_t)c * 20);
#pragma unroll
        for (int q = 0; q < 5; ++q) {
            const float4 v = wp[q];
            wreg[q * 4 + 0] = v.x; wreg[q * 4 + 1] = v.y;
            wreg[q * 4 + 2] = v.z; wreg[q * 4 + 3] = v.w;
        }
    }
    const float4 breg = *(const float4*)(cb + (size_t)c * 4);

    // stage xs: global reads coalesced in t, LDS writes stride-33 (no conflict)
    const float* xrow = x + ((size_t)b * C_ + c0) * T_;
    for (int i = tid; i < 32 * 132; i += 256) {
        const int cc = i / 132;
        const int j  = i - cc * 132;
        const int t  = t0 - 2 + j;
        float v = 0.f;
        if (t >= 0 && t < T_) v = xrow[(size_t)cc * T_ + t];
        xs[j][cc] = v;
    }
    __syncthreads();

    unsigned short* erow = enc + (size_t)(b * T_ + t0) * 512 + c * 4;
#pragma unroll
    for (int tt = 0; tt < 16; ++tt) {
        const int tl = tl0 + (tt << 3);
        const float x0 = xs[tl][c_l],     x1 = xs[tl + 1][c_l],
                    x2 = xs[tl + 2][c_l], x3 = xs[tl + 3][c_l],
                    x4 = xs[tl + 4][c_l];
        ushort4 hv;
        {
            const float a0 = breg.x + wreg[0]*x0 + wreg[1]*x1 + wreg[2]*x2 + wreg[3]*x3 + wreg[4]*x4;
            const float a1 = breg.y + wreg[5]*x0 + wreg[6]*x1 + wreg[7]*x2 + wreg[8]*x3 + wreg[9]*x4;
            const float a2 = breg.z + wreg[10]*x0 + wreg[11]*x1 + wreg[12]*x2 + wreg[13]*x3 + wreg[14]*x4;
            const float a3 = breg.w + wreg[15]*x0 + wreg[16]*x1 + wreg[17]*x2 + wreg[18]*x3 + wreg[19]*x4;
            hv.x = f2bf(a0); hv.y = f2bf(a1); hv.z = f2bf(a2); hv.w = f2bf(a3);
        }
        *(ushort4*)(erow + (size_t)tl * 512) = hv;
    }
}

// ---------------------------------------------------------------------------
// bf16 MFMA GEMM, 128x128 tile, BK=64, 4 waves. global_load_lds staging with
// inverse-swizzled SOURCE (rule 21): LDS dest linear, reads XOR-swizzled.
// MODE 0: D[m=(b,t)][n=h] = enc @ w1b^T + b1; out bf16, LDS-staged coalesced.
// MODE 1: D[m=c][n=(b,t)] = Weffb @ mem^T + beff; out fp32 direct (B,C,T).
// ---------------------------------------------------------------------------
template<int MODE>
__global__ __launch_bounds__(256) void k_mfma(
    const unsigned short* __restrict__ A, const unsigned short* __restrict__ Bm,
    const float* __restrict__ bias, void* __restrict__ outp)
{
    __shared__ unsigned char lds[32768];  // As 16KB | Bs 16KB
    const int tid = threadIdx.x;
    const int lane = tid & 63;
    const int w = tid >> 6;
    const int wm = (w & 1) << 6, wn = (w >> 1) << 6;

    int m0, n0;
    if (MODE == 0) {
        const int d = blockIdx.x;
        const int g = ((d & 7) << 8) + (d >> 3);  // XCD-contiguous tiles
        m0 = (g >> 2) << 7;
        n0 = (g & 3) << 7;
    } else {
        m0 = 0;
        n0 = blockIdx.x << 7;
    }

    // pre-swizzled per-lane global source: LDS row = 8-row groups, 128B k-slice
    const int lrow = lane >> 3;                  // row within 8-row group
    const int lcol = ((lane & 7) ^ lrow) << 4;   // swizzled 16B slot
    const unsigned char* pA = (const unsigned char*)A +
        (size_t)(m0 + w * 32 + lrow) * 1024 + lcol;
    const unsigned char* pB = (const unsigned char*)Bm +
        (size_t)(n0 + w * 32 + lrow) * 1024 + lcol;
    unsigned char* lA = lds + w * 4096;
    unsigned char* lB = lds + 16384 + w * 4096;

    v4f acc[4][4];
#pragma unroll
    for (int i = 0; i < 4; ++i)
#pragma unroll
        for (int j = 0; j < 4; ++j) acc[i][j] = (v4f)0.f;

    for (int k0 = 0; k0 < 512; k0 += 64) {
        __syncthreads();  // prior iteration's LDS reads done
#pragma unroll
        for (int i = 0; i < 4; ++i) {
            GL16(pA + (size_t)i * 8192 + k0 * 2, lA + i * 1024);
            GL16(pB + (size_t)i * 8192 + k0 * 2, lB + i * 1024);
        }
        __syncthreads();  // vmcnt drain: tiles resident
#pragma unroll
        for (int ks = 0; ks < 2; ++ks) {
            v8s af[4], bfr[4];
#pragma unroll
            for (int i = 0; i < 4; ++i) {
                const int ra = wm + i * 16 + (lane & 15);
                const int rb = wn + i * 16 + (lane & 15);
                const int kb = ks * 64 + ((lane >> 4) << 4);
                af[i]  = *(const v8s*)(lds + ra * 128 + (kb ^ ((ra & 7) << 4)));
                bfr[i] = *(const v8s*)(lds + 16384 + rb * 128 + (kb ^ ((rb & 7) << 4)));
            }
#pragma unroll
            for (int mi = 0; mi < 4; ++mi)
#pragma unroll
                for (int ni = 0; ni < 4; ++ni)
                    acc[mi][ni] = __builtin_amdgcn_mfma_f32_16x16x32_bf16(
                        af[mi], bfr[ni], acc[mi][ni], 0, 0, 0);
        }
    }

    if (MODE == 0) {
        // stage C-tile (128x128 bf16 = 32KB) into LDS, swizzled; store coalesced
        __syncthreads();
#pragma unroll
        for (int mi = 0; mi < 4; ++mi)
#pragma unroll
            for (int ni = 0; ni < 4; ++ni) {
                const int n = wn + ni * 16 + (lane & 15);
                const float bi = bias[n0 + n];
#pragma unroll
                for (int r = 0; r < 4; ++r) {
                    const int m = wm + mi * 16 + ((lane >> 4) << 2) + r;
                    *(unsigned short*)(lds + m * 256 +
                        ((n * 2) ^ (((m >> 2) & 3) << 5))) =
                        f2bf(acc[mi][ni][r] + bi);
                }
            }
        __syncthreads();
        unsigned short* out = (unsigned short*)outp;
#pragma unroll
        for (int s = 0; s < 8; ++s) {
            const int idx = s * 256 + tid;
            const int r = idx >> 4, c16 = idx & 15;
            const int4 v = *(const int4*)(lds + r * 256 +
                ((c16 * 16) ^ (((r >> 2) & 3) << 5)));
            *(int4*)(&out[(size_t)(m0 + r) * 512 + n0 + c16 * 8]) = v;
        }
    } else {
        float* out = (float*)outp;
#pragma unroll
        for (int mi = 0; mi < 4; ++mi)
#pragma unroll
            for (int ni = 0; ni < 4; ++ni) {
                const int n = n0 + wn + ni * 16 + (lane & 15);  // (b,t)
                const int b = n >> 10, t = n & 1023;
#pragma unroll
                for (int r = 0; r < 4; ++r) {
                    const int c = wm + mi * 16 + ((lane >> 4) << 2) + r;
                    out[((size_t)(b * C_ + c) << 10) + t] = acc[mi][ni][r] + bias[c];
                }
            }
    }
}

// ---------------------------------------------------------------------------
// LIF recurrence. 4-way t-split with 128-step warmup (alpha^128 ~ 1.7e-3,
// |mem| ~ 0.02 << threshold 1.0 -> warmup error ~3e-4, spikes unaffected).
// Reads immutable hid (bf16), writes mem into memb (the dead enc slot).
// ---------------------------------------------------------------------------
__global__ __launch_bounds__(256) void k_recur(
    const unsigned int* __restrict__ hid, unsigned int* __restrict__ memb)
{
    const int j = blockIdx.x >> 6;       // t-chunk 0..3
    const int b = blockIdx.x & 63;
    const size_t base = (size_t)b * 262144 + threadIdx.x;  // uint units
    const unsigned int* pin = hid + base;
    unsigned int* pout = memb + base;
    float ma = 0.f, mb = 0.f;
    const int t0 = j << 8;

    if (j > 0) {  // warmup: read-only, mem assumed 0 at t0-128
        for (int t = t0 - 128; t < t0; t += 16) {
            unsigned int v[16];
#pragma unroll
            for (int i = 0; i < 16; ++i) v[i] = pin[(size_t)(t + i) << 8];
#pragma unroll
            for (int i = 0; i < 16; ++i) {
                ma = ALPHA_F * ma + ONEMA_F * bf2f((unsigned short)(v[i] & 0xFFFFu));
                ma = (ma >= 1.0f) ? 0.f : ma;
                mb = ALPHA_F * mb + ONEMA_F * bf2f((unsigned short)(v[i] >> 16));
                mb = (mb >= 1.0f) ? 0.f : mb;
            }
        }
    }
    for (int t = t0; t < t0 + 256; t += 16) {
        unsigned int v[16];
#pragma unroll
        for (int i = 0; i < 16; ++i) v[i] = pin[(size_t)(t + i) << 8];
#pragma unroll
        for (int i = 0; i < 16; ++i) {
            ma = ALPHA_F * ma + ONEMA_F * bf2f((unsigned short)(v[i] & 0xFFFFu));
            ma = (ma >= 1.0f) ? 0.f : ma;
            mb = ALPHA_F * mb + ONEMA_F * bf2f((unsigned short)(v[i] >> 16));
            mb = (mb >= 1.0f) ? 0.f : mb;
            v[i] = (unsigned)f2bf(ma) | ((unsigned)f2bf(mb) << 16);
        }
#pragma unroll
        for (int i = 0; i < 16; ++i) pout[(size_t)(t + i) << 8] = v[i];
    }
}

// ---------------------------------------------------------------------------
extern "C" void kernel_launch(void* const* d_in, const int* in_sizes, int n_in,
                              void* d_out, int out_size, void* d_ws, size_t ws_size,
                              hipStream_t stream)
{
    const float* x   = (const float*)d_in[0];
    const float* cw  = (const float*)d_in[1];
    const float* cb  = (const float*)d_in[2];
    const float* w1  = (const float*)d_in[3];
    const float* b1  = (const float*)d_in[4];
    const float* w2  = (const float*)d_in[5];
    const float* b2  = (const float*)d_in[6];
    const float* og  = (const float*)d_in[7];

    char* ws = (char*)d_ws;
    unsigned short* enc   = (unsigned short*)ws;               // 64 MiB (later: memb)
    unsigned short* hid   = (unsigned short*)(ws + 67108864);  // 64 MiB
    unsigned short* Weffb = (unsigned short*)(ws + 134217728); // 128 KiB
    float*          beff  = (float*)(ws + 134479872);          // 512 B
    unsigned short* w1b   = (unsigned short*)d_out;            // temp, dead before mfma<1>

    k_cast<<<256, 256, 0, stream>>>(w1, w1b, 65536);
    k_conv<<<2048, 256, 0, stream>>>(x, cw, cb, enc);
    k_weff<<<128, 128, 0, stream>>>(w2, b2, og, Weffb, beff);

    k_mfma<0><<<2048, 256, 0, stream>>>(enc, w1b, b1, hid);
    k_recur<<<256, 256, 0, stream>>>((const unsigned int*)hid, (unsigned int*)enc);
    k_mfma<1><<<512, 256, 0, stream>>>(Weffb, enc, beff, (float*)d_out);
}

// Round 5
// 120.592 us; speedup vs baseline: 6.3348x; 1.0681x over previous
//
#include <hip/hip_runtime.h>
#include <cstddef>
#include <cstdint>

constexpr int B_ = 64, C_ = 128, T_ = 1024, H_ = 512, ENC_ = 512;
#define ALPHA_F 0.9512294245007140f
#define ONEMA_F 0.0487705754992860f

typedef short v8s __attribute__((ext_vector_type(8)));
typedef float v4f __attribute__((ext_vector_type(4)));

#define GL16(gp, lp) __builtin_amdgcn_global_load_lds( \
    (const __attribute__((address_space(1))) unsigned int*)(gp), \
    (__attribute__((address_space(3))) unsigned int*)(lp), 16, 0, 0)

__device__ __forceinline__ unsigned short f2bf(float f) {
    union { float f; unsigned u; } v; v.f = f;
    unsigned r = v.u + 0x7FFFu + ((v.u >> 16) & 1u);
    return (unsigned short)(r >> 16);
}
__device__ __forceinline__ float bf2f(unsigned short h) {
    union { unsigned u; float f; } v; v.u = ((unsigned)h) << 16;
    return v.f;
}

// ---------------------------------------------------------------------------
// cast w1 (fp32) -> bf16
// ---------------------------------------------------------------------------
__global__ __launch_bounds__(256) void k_cast(
    const float* __restrict__ in, unsigned short* __restrict__ out, int n4)
{
    int i = blockIdx.x * 256 + threadIdx.x;
    if (i < n4) {
        float4 v = ((const float4*)in)[i];
        ushort4 h;
        h.x = f2bf(v.x); h.y = f2bf(v.y); h.z = f2bf(v.z); h.w = f2bf(v.w);
        ((ushort4*)out)[i] = h;
    }
}

// ---------------------------------------------------------------------------
// W_eff = (I + gate) @ w2 -> bf16,  b_eff = (I + gate) @ b2 -> fp32
// ---------------------------------------------------------------------------
__global__ __launch_bounds__(128) void k_weff(
    const float* __restrict__ w2, const float* __restrict__ b2,
    const float* __restrict__ og, unsigned short* __restrict__ Weffb,
    float* __restrict__ beff)
{
    const int c = blockIdx.x;
    const int tid = threadIdx.x;
    __shared__ float ogs[C_];
    float g = og[c * C_ + tid];
    if (tid == c) g = 0.f;
    ogs[tid] = g;
    __syncthreads();

    float acc[4];
#pragma unroll
    for (int s = 0; s < 4; ++s) acc[s] = w2[c * H_ + tid + s * 128];
    for (int cp = 0; cp < C_; ++cp) {
        const float w = ogs[cp];
#pragma unroll
        for (int s = 0; s < 4; ++s) acc[s] += w * w2[cp * H_ + tid + s * 128];
    }
#pragma unroll
    for (int s = 0; s < 4; ++s) Weffb[c * H_ + tid + s * 128] = f2bf(acc[s]);

    if (tid == 0) {
        float a = b2[c];
        for (int cp = 0; cp < C_; ++cp) a += ogs[cp] * b2[cp];
        beff[c] = a;
    }
}

// ---------------------------------------------------------------------------
// depthwise conv (K=5, same-pad) -> enc bf16 [B*T][ENC]
// ---------------------------------------------------------------------------
__global__ __launch_bounds__(256) void k_conv(
    const float* __restrict__ x, const float* __restrict__ cw,
    const float* __restrict__ cb, unsigned short* __restrict__ enc)
{
    const int bid = blockIdx.x;
    const int b  = bid >> 5;
    const int t0 = ((bid >> 2) & 7) << 7;
    const int c0 = (bid & 3) << 5;
    const int tid = threadIdx.x;
    const int c_l = tid & 31;
    const int tl0 = tid >> 5;

    __shared__ float xs[132][33];

    const int c = c0 + c_l;
    float wreg[20];
    {
        const float4* wp = (const float4*)(cw + (size_t)c * 20);
#pragma unroll
        for (int q = 0; q < 5; ++q) {
            const float4 v = wp[q];
            wreg[q * 4 + 0] = v.x; wreg[q * 4 + 1] = v.y;
            wreg[q * 4 + 2] = v.z; wreg[q * 4 + 3] = v.w;
        }
    }
    const float4 breg = *(const float4*)(cb + (size_t)c * 4);

    const float* xrow = x + ((size_t)b * C_ + c0) * T_;
    for (int i = tid; i < 32 * 132; i += 256) {
        const int cc = i / 132;
        const int j  = i - cc * 132;
        const int t  = t0 - 2 + j;
        float v = 0.f;
        if (t >= 0 && t < T_) v = xrow[(size_t)cc * T_ + t];
        xs[j][cc] = v;
    }
    __syncthreads();

    unsigned short* erow = enc + (size_t)(b * T_ + t0) * 512 + c * 4;
#pragma unroll
    for (int tt = 0; tt < 16; ++tt) {
        const int tl = tl0 + (tt << 3);
        const float x0 = xs[tl][c_l],     x1 = xs[tl + 1][c_l],
                    x2 = xs[tl + 2][c_l], x3 = xs[tl + 3][c_l],
                    x4 = xs[tl + 4][c_l];
        ushort4 hv;
        {
            const float a0 = breg.x + wreg[0]*x0 + wreg[1]*x1 + wreg[2]*x2 + wreg[3]*x3 + wreg[4]*x4;
            const float a1 = breg.y + wreg[5]*x0 + wreg[6]*x1 + wreg[7]*x2 + wreg[8]*x3 + wreg[9]*x4;
            const float a2 = breg.z + wreg[10]*x0 + wreg[11]*x1 + wreg[12]*x2 + wreg[13]*x3 + wreg[14]*x4;
            const float a3 = breg.w + wreg[15]*x0 + wreg[16]*x1 + wreg[17]*x2 + wreg[18]*x3 + wreg[19]*x4;
            hv.x = f2bf(a0); hv.y = f2bf(a1); hv.z = f2bf(a2); hv.w = f2bf(a3);
        }
        *(ushort4*)(erow + (size_t)tl * 512) = hv;
    }
}

// ---------------------------------------------------------------------------
// GEMM1, 8-phase 256x256 template (T2+T3+T4+T5), BK=64, 8 waves (2M x 4N).
// hid[m=(b,t)][n=h] = enc @ w1b^T + b1, out bf16 via LDS-staged stores.
// buf0 holds even K-tiles, buf1 odd. Per phase: ds-read subtile | stage one
// 16KB half-tile (2 x global_load_lds, pre-swizzled source) | barrier |
// 16 MFMA (setprio-wrapped) | barrier. vmcnt(4) only at phases 4 & 8.
// Stage schedule (iter j: compute kt=2j in buf0 p1-4, kt=2j+1 in buf1 p5-8):
//   p1,p2: buf1.A(2j+1)  p3,p4: buf0.B(2j+2)  p5,p6: buf0.A(2j+2)
//   p7,p8: buf1.B(2j+3)   -- each >=2 barriers after last read of its target,
//   landing gated by the preceding vmcnt(4)+barrier. Tail stages wrap (&7).
// ---------------------------------------------------------------------------
__global__ __launch_bounds__(512, 2) void k_gemm1_8p(
    const unsigned short* __restrict__ A, const unsigned short* __restrict__ Bw,
    const float* __restrict__ bias, unsigned short* __restrict__ out)
{
    __shared__ unsigned char lds[131072];  // buf0:A[0,32K)B[32K,64K) buf1:A[64K,96K)B[96K,128K)
    const int tid = threadIdx.x;
    const int lane = tid & 63;
    const int w = tid >> 6;
    const int wr = w >> 2;          // m-half (128 rows)
    const int wc = w & 3;           // n-quarter (64 cols)
    const int l15 = lane & 15;
    const int klo = lane >> 4;

    const int d = blockIdx.x;                 // 512 blocks
    const int g = ((d & 7) << 6) + (d >> 3);  // XCD-contiguous (512%8==0)
    const int m0 = (g >> 1) << 8;
    const int n0 = (g & 1) << 8;

    const int srow = tid >> 3;                       // 0..63
    const int scol = ((tid & 7) ^ (srow & 7)) << 4;  // inverse-swizzled src slot

    const unsigned char* Ag = (const unsigned char*)A;
    const unsigned char* Bg = (const unsigned char*)Bw;

    v4f acc[8][4];
#pragma unroll
    for (int i = 0; i < 8; ++i)
#pragma unroll
        for (int j = 0; j < 4; ++j) acc[i][j] = (v4f)0.f;

    v8s pa[2][2], pb[4][2];

#define STAGE(bufb, isB, h, ktv) do { \
    const unsigned char* sg_ = ((isB) ? Bg : Ag) + \
        (size_t)(((isB) ? n0 : m0) + (h)*128 + srow) * 1024 + (ktv)*128 + scol; \
    unsigned char* sl_ = lds + (bufb)*65536 + (isB)*32768 + (h)*16384 + tid*16; \
    GL16(sg_, sl_); \
    GL16(sg_ + 65536, sl_ + 8192); \
} while(0)

#define LDA8(bufb, q) do { \
    _Pragma("unroll") \
    for (int mi2_ = 0; mi2_ < 2; ++mi2_) { \
      _Pragma("unroll") \
      for (int ks_ = 0; ks_ < 2; ++ks_) { \
        const int row_ = wr*128 + ((q)*2 + mi2_)*16 + l15; \
        pa[mi2_][ks_] = *(const v8s*)(lds + (bufb)*65536 + row_*128 + \
            ((ks_*64 + klo*16) ^ ((row_ & 7) << 4))); \
      } } \
} while(0)

#define LDB8(bufb) do { \
    _Pragma("unroll") \
    for (int ni_ = 0; ni_ < 4; ++ni_) { \
      _Pragma("unroll") \
      for (int ks_ = 0; ks_ < 2; ++ks_) { \
        const int n_ = wc*64 + ni_*16 + l15; \
        pb[ni_][ks_] = *(const v8s*)(lds + (bufb)*65536 + 32768 + n_*128 + \
            ((ks_*64 + klo*16) ^ ((n_ & 7) << 4))); \
      } } \
} while(0)

#define MM8(q) do { \
    __builtin_amdgcn_s_setprio(1); \
    _Pragma("unroll") \
    for (int mi2_ = 0; mi2_ < 2; ++mi2_) \
      _Pragma("unroll") \
      for (int ni_ = 0; ni_ < 4; ++ni_) \
        _Pragma("unroll") \
        for (int ks_ = 0; ks_ < 2; ++ks_) \
          acc[(q)*2+mi2_][ni_] = __builtin_amdgcn_mfma_f32_16x16x32_bf16( \
              pa[mi2_][ks_], pb[ni_][ks_], acc[(q)*2+mi2_][ni_], 0, 0, 0); \
    __builtin_amdgcn_s_setprio(0); \
} while(0)

#define BAR8() do { __builtin_amdgcn_sched_barrier(0); \
    __builtin_amdgcn_s_barrier(); \
    __builtin_amdgcn_sched_barrier(0); } while(0)
#define WVM(n) do { asm volatile("s_waitcnt vmcnt(" #n ")" ::: "memory"); \
    __builtin_amdgcn_sched_barrier(0); } while(0)

    // prologue: buf0 full (kt0) + buf1.B (kt1); FIFO matches steady state
    STAGE(0,1,0,0); STAGE(0,1,1,0);
    STAGE(0,0,0,0); STAGE(0,0,1,0);
    STAGE(1,1,0,1); STAGE(1,1,1,1);
    WVM(4); BAR8();

    for (int j = 0; j < 4; ++j) {
        const int sA  = 2*j + 1;
        const int sB0 = (2*j + 2) & 7;
        const int sB1 = (2*j + 3) & 7;
        // p1..p4: compute kt=2j from buf0
        LDA8(0,0); LDB8(0); STAGE(1,0,0,sA);  BAR8(); MM8(0); BAR8();
        LDA8(0,1);          STAGE(1,0,1,sA);  BAR8(); MM8(1); BAR8();
        LDA8(0,2);          STAGE(0,1,0,sB0); BAR8(); MM8(2); BAR8();
        LDA8(0,3);          STAGE(0,1,1,sB0); BAR8(); MM8(3); WVM(4); BAR8();
        // p5..p8: compute kt=2j+1 from buf1
        LDA8(1,0); LDB8(1); STAGE(0,0,0,sB0); BAR8(); MM8(0); BAR8();
        LDA8(1,1);          STAGE(0,0,1,sB0); BAR8(); MM8(1); BAR8();
        LDA8(1,2);          STAGE(1,1,0,sB1); BAR8(); MM8(2); BAR8();
        LDA8(1,3);          STAGE(1,1,1,sB1); BAR8(); MM8(3); WVM(4); BAR8();
    }

    WVM(0); BAR8();

    // epilogue: C tile (256 x 256 bf16 = 128KB) via LDS, coalesced 512B rows
#pragma unroll
    for (int mi = 0; mi < 8; ++mi)
#pragma unroll
        for (int ni = 0; ni < 4; ++ni) {
            const int n = wc*64 + ni*16 + l15;
            const float bi = bias[n0 + n];
#pragma unroll
            for (int r = 0; r < 4; ++r) {
                const int m = wr*128 + mi*16 + klo*4 + r;
                *(unsigned short*)(lds + m*512 + ((2*n) ^ ((m & 7) << 4))) =
                    f2bf(acc[mi][ni][r] + bi);
            }
        }
    BAR8();
#pragma unroll
    for (int it = 0; it < 16; ++it) {
        const int idx = it*512 + tid;
        const int r = idx >> 5, s = idx & 31;
        const int4 v = *(const int4*)(lds + r*512 + ((s*16) ^ ((r & 7) << 4)));
        *(int4*)(&out[(size_t)(m0 + r)*512 + n0 + s*8]) = v;
    }
#undef STAGE
#undef LDA8
#undef LDB8
#undef MM8
#undef BAR8
#undef WVM
}

// ---------------------------------------------------------------------------
// GEMM2 (old 128x128 structure): D[m=c][n=(b,t)] = Weffb @ mem^T + beff,
// out fp32 direct in (B,C,T).
// ---------------------------------------------------------------------------
__global__ __launch_bounds__(256) void k_mfma1(
    const unsigned short* __restrict__ A, const unsigned short* __restrict__ Bm,
    const float* __restrict__ bias, float* __restrict__ out)
{
    __shared__ unsigned char lds[32768];
    const int tid = threadIdx.x;
    const int lane = tid & 63;
    const int w = tid >> 6;
    const int wm = (w & 1) << 6, wn = (w >> 1) << 6;

    const int m0 = 0;
    const int n0 = blockIdx.x << 7;

    const int lrow = lane >> 3;
    const int lcol = ((lane & 7) ^ lrow) << 4;
    const unsigned char* pA = (const unsigned char*)A +
        (size_t)(m0 + w * 32 + lrow) * 1024 + lcol;
    const unsigned char* pB = (const unsigned char*)Bm +
        (size_t)(n0 + w * 32 + lrow) * 1024 + lcol;
    unsigned char* lA = lds + w * 4096;
    unsigned char* lB = lds + 16384 + w * 4096;

    v4f acc[4][4];
#pragma unroll
    for (int i = 0; i < 4; ++i)
#pragma unroll
        for (int j = 0; j < 4; ++j) acc[i][j] = (v4f)0.f;

    for (int k0 = 0; k0 < 512; k0 += 64) {
        __syncthreads();
#pragma unroll
        for (int i = 0; i < 4; ++i) {
            GL16(pA + (size_t)i * 8192 + k0 * 2, lA + i * 1024);
            GL16(pB + (size_t)i * 8192 + k0 * 2, lB + i * 1024);
        }
        __syncthreads();
#pragma unroll
        for (int ks = 0; ks < 2; ++ks) {
            v8s af[4], bfr[4];
#pragma unroll
            for (int i = 0; i < 4; ++i) {
                const int ra = wm + i * 16 + (lane & 15);
                const int rb = wn + i * 16 + (lane & 15);
                const int kb = ks * 64 + ((lane >> 4) << 4);
                af[i]  = *(const v8s*)(lds + ra * 128 + (kb ^ ((ra & 7) << 4)));
                bfr[i] = *(const v8s*)(lds + 16384 + rb * 128 + (kb ^ ((rb & 7) << 4)));
            }
#pragma unroll
            for (int mi = 0; mi < 4; ++mi)
#pragma unroll
                for (int ni = 0; ni < 4; ++ni)
                    acc[mi][ni] = __builtin_amdgcn_mfma_f32_16x16x32_bf16(
                        af[mi], bfr[ni], acc[mi][ni], 0, 0, 0);
        }
    }

#pragma unroll
    for (int mi = 0; mi < 4; ++mi)
#pragma unroll
        for (int ni = 0; ni < 4; ++ni) {
            const int n = n0 + wn + ni * 16 + (lane & 15);  // (b,t)
            const int b = n >> 10, t = n & 1023;
#pragma unroll
            for (int r = 0; r < 4; ++r) {
                const int c = wm + mi * 16 + ((lane >> 4) << 2) + r;
                out[((size_t)(b * C_ + c) << 10) + t] = acc[mi][ni][r] + bias[c];
            }
        }
}

// ---------------------------------------------------------------------------
// LIF recurrence. 4-way t-split with 128-step warmup.
// ---------------------------------------------------------------------------
__global__ __launch_bounds__(256) void k_recur(
    const unsigned int* __restrict__ hid, unsigned int* __restrict__ memb)
{
    const int j = blockIdx.x >> 6;
    const int b = blockIdx.x & 63;
    const size_t base = (size_t)b * 262144 + threadIdx.x;
    const unsigned int* pin = hid + base;
    unsigned int* pout = memb + base;
    float ma = 0.f, mb = 0.f;
    const int t0 = j << 8;

    if (j > 0) {
        for (int t = t0 - 128; t < t0; t += 16) {
            unsigned int v[16];
#pragma unroll
            for (int i = 0; i < 16; ++i) v[i] = pin[(size_t)(t + i) << 8];
#pragma unroll
            for (int i = 0; i < 16; ++i) {
                ma = ALPHA_F * ma + ONEMA_F * bf2f((unsigned short)(v[i] & 0xFFFFu));
                ma = (ma >= 1.0f) ? 0.f : ma;
                mb = ALPHA_F * mb + ONEMA_F * bf2f((unsigned short)(v[i] >> 16));
                mb = (mb >= 1.0f) ? 0.f : mb;
            }
        }
    }
    for (int t = t0; t < t0 + 256; t += 16) {
        unsigned int v[16];
#pragma unroll
        for (int i = 0; i < 16; ++i) v[i] = pin[(size_t)(t + i) << 8];
#pragma unroll
        for (int i = 0; i < 16; ++i) {
            ma = ALPHA_F * ma + ONEMA_F * bf2f((unsigned short)(v[i] & 0xFFFFu));
            ma = (ma >= 1.0f) ? 0.f : ma;
            mb = ALPHA_F * mb + ONEMA_F * bf2f((unsigned short)(v[i] >> 16));
            mb = (mb >= 1.0f) ? 0.f : mb;
            v[i] = (unsigned)f2bf(ma) | ((unsigned)f2bf(mb) << 16);
        }
#pragma unroll
        for (int i = 0; i < 16; ++i) pout[(size_t)(t + i) << 8] = v[i];
    }
}

// ---------------------------------------------------------------------------
extern "C" void kernel_launch(void* const* d_in, const int* in_sizes, int n_in,
                              void* d_out, int out_size, void* d_ws, size_t ws_size,
                              hipStream_t stream)
{
    const float* x   = (const float*)d_in[0];
    const float* cw  = (const float*)d_in[1];
    const float* cb  = (const float*)d_in[2];
    const float* w1  = (const float*)d_in[3];
    const float* b1  = (const float*)d_in[4];
    const float* w2  = (const float*)d_in[5];
    const float* b2  = (const float*)d_in[6];
    const float* og  = (const float*)d_in[7];

    char* ws = (char*)d_ws;
    unsigned short* enc   = (unsigned short*)ws;               // 64 MiB (later: memb)
    unsigned short* hid   = (unsigned short*)(ws + 67108864);  // 64 MiB
    unsigned short* Weffb = (unsigned short*)(ws + 134217728); // 128 KiB
    float*          beff  = (float*)(ws + 134479872);          // 512 B
    unsigned short* w1b   = (unsigned short*)d_out;            // temp, dead before k_mfma1

    k_cast<<<256, 256, 0, stream>>>(w1, w1b, 65536);
    k_conv<<<2048, 256, 0, stream>>>(x, cw, cb, enc);
    k_weff<<<128, 128, 0, stream>>>(w2, b2, og, Weffb, beff);

    k_gemm1_8p<<<512, 512, 0, stream>>>(enc, w1b, b1, hid);
    k_recur<<<256, 256, 0, stream>>>((const unsigned int*)hid, (unsigned int*)enc);
    k_mfma1<<<512, 256, 0, stream>>>(Weffb, enc, beff, (float*)d_out);
}